// Round 10
// baseline (1020.125 us; speedup 1.0000x reference)
//
#include <hip/hip_runtime.h>
#include <hip/hip_bf16.h>
#include <cstdint>
#include <math.h>

// ---------------------------------------------------------------------------
// AdaptiveMCTSReasoner  B=16, S=1024, H=1024, MAX_SIMS=100, K_FOCUS=3
// Round 10: kill convert-in-staging (round-9 profile: agg1 ABF=0 at
// MfmaUtil 12.8%, VALU 35% = VALU-staging-bound). Pre-convert big fp32
// operands to bf16 ONCE (bit-identical RNE), run all bulk GEMMs through the
// pure global_load_lds ABF=1 path (dual-source + gather added). Policy gets
// pre-split root hi/lo and stages via gll too. Workspace is tier-gated at
// runtime on ws_size; fallback = round-9 behavior (passing).
// ---------------------------------------------------------------------------

#define SEQ 1024
#define BATCH 16
#define HDIM 1024
#define NSIM 100
#define NCHAIN (NSIM * BATCH)   // 1600
#define SHC (SEQ * HDIM)

typedef short bf16x8 __attribute__((ext_vector_type(8)));
typedef float f32x4 __attribute__((ext_vector_type(4)));
typedef float float4v __attribute__((ext_vector_type(4)));

__device__ __forceinline__ unsigned short f2bf(float f) {
    union { float f; uint32_t u; } c; c.f = f;
    uint32_t u = c.u;
    return (unsigned short)((u + 0x7FFFu + ((u >> 16) & 1u)) >> 16);   // RNE
}
__device__ __forceinline__ float bf2f(unsigned short h) {
    union { uint32_t u; float f; } c; c.u = ((uint32_t)h) << 16;
    return c.f;
}

__device__ __forceinline__ void gll16(const void* g, void* l) {
    __builtin_amdgcn_global_load_lds(
        (const __attribute__((address_space(1))) void*)g,
        (__attribute__((address_space(3))) void*)l, 16, 0, 0);
}

__device__ __forceinline__ float gelu32(float x) {
    return 0.5f * x * (1.0f + erff(x * 0.70710678f));
}

// XCD-aware bijective swizzle (requires nwg % 8 == 0; all our grids qualify)
__device__ __forceinline__ void swz_block(int& bx, int& by) {
    int gx = gridDim.x;
    int h = blockIdx.y * gx + blockIdx.x;
    int nwg = gx * gridDim.y;
    int l = (h & 7) * (nwg >> 3) + (h >> 3);
    bx = l % gx; by = l / gx;
}

// ------------------------------- threefry ----------------------------------
__device__ __forceinline__ uint32_t rotl32(uint32_t v, int r) {
    return (v << r) | (v >> (32 - r));
}

__device__ __forceinline__ void threefry(uint32_t k0, uint32_t k1,
                                         uint32_t c0, uint32_t c1,
                                         uint32_t& o0, uint32_t& o1) {
    uint32_t ks0 = k0, ks1 = k1, ks2 = k0 ^ k1 ^ 0x1BD11BDAu;
    uint32_t x0 = c0 + ks0, x1 = c1 + ks1;
#define TFR(r) { x0 += x1; x1 = rotl32(x1, r); x1 ^= x0; }
    TFR(13) TFR(15) TFR(26) TFR(6)   x0 += ks1; x1 += ks2 + 1u;
    TFR(17) TFR(29) TFR(16) TFR(24)  x0 += ks2; x1 += ks0 + 2u;
    TFR(13) TFR(15) TFR(26) TFR(6)   x0 += ks0; x1 += ks1 + 3u;
    TFR(17) TFR(29) TFR(16) TFR(24)  x0 += ks1; x1 += ks2 + 4u;
    TFR(13) TFR(15) TFR(26) TFR(6)   x0 += ks2; x1 += ks0 + 5u;
#undef TFR
    o0 = x0; o1 = x1;
}

__device__ __forceinline__ bool better(float va, int ia, float vb, int ib) {
    return (va > vb) || (va == vb && ia < ib);
}

// ----------------- weight transpose+convert: WT[n][k] = bf16(W[k][n]) ------
__global__ __launch_bounds__(256)
void transpose_bf16(const float* __restrict__ W, unsigned short* __restrict__ WT,
                    int K, int N) {
    __shared__ float t[32][33];
    int kb = blockIdx.x * 32, nb = blockIdx.y * 32;
    int tx = threadIdx.x & 31, ty4 = threadIdx.x >> 5;
#pragma unroll
    for (int p = 0; p < 4; ++p) {
        int ky = ty4 + p * 8;
        t[ky][tx] = W[(long)(kb + ky) * N + nb + tx];
    }
    __syncthreads();
#pragma unroll
    for (int p = 0; p < 4; ++p) {
        int ny = ty4 + p * 8;
        WT[(long)(nb + ny) * K + kb + tx] = f2bf(t[tx][ny]);
    }
}

// hi/lo split transpose for Wp1
__global__ __launch_bounds__(256)
void transpose_split(const float* __restrict__ W, unsigned short* __restrict__ Whi,
                     unsigned short* __restrict__ Wlo, int K, int N) {
    __shared__ float t[32][33];
    int kb = blockIdx.x * 32, nb = blockIdx.y * 32;
    int tx = threadIdx.x & 31, ty4 = threadIdx.x >> 5;
#pragma unroll
    for (int p = 0; p < 4; ++p) {
        int ky = ty4 + p * 8;
        t[ky][tx] = W[(long)(kb + ky) * N + nb + tx];
    }
    __syncthreads();
#pragma unroll
    for (int p = 0; p < 4; ++p) {
        int ny = ty4 + p * 8;
        float w = t[tx][ny];
        unsigned short h = f2bf(w);
        Whi[(long)(nb + ny) * K + kb + tx] = h;
        Wlo[(long)(nb + ny) * K + kb + tx] = f2bf(w - bf2f(h));
    }
}

// ---------- fp32 -> bf16 (hi) [+ optional lo split], bit-identical RNE ------
__global__ __launch_bounds__(256)
void cvt_split(const float* __restrict__ src, unsigned short* __restrict__ hi,
               unsigned short* __restrict__ lo, long n8) {
    long i = (long)blockIdx.x * 256 + threadIdx.x;
    long stride = (long)gridDim.x * 256;
    for (; i < n8; i += stride) {
        const float* s = src + i * 8;
        float4v v0 = *(const float4v*)s;
        float4v v1 = *(const float4v*)(s + 4);
        bf16x8 h, l;
#pragma unroll
        for (int e = 0; e < 4; ++e) {
            unsigned short h0 = f2bf(v0[e]);
            h[e] = (short)h0;
            unsigned short h1 = f2bf(v1[e]);
            h[e + 4] = (short)h1;
            if (lo) {
                l[e] = (short)f2bf(v0[e] - bf2f(h0));
                l[e + 4] = (short)f2bf(v1[e] - bf2f(h1));
            }
        }
        *(bf16x8*)&hi[i * 8] = h;
        if (lo) *(bf16x8*)&lo[i * 8] = l;
    }
}

// ------------------------- GEMM (bf16 MFMA, B^T weights) --------------------
// TM = tile rows (128 or 64). 4 waves as 2x2; wave tile (TM/2) x 64.
// ABF=1: A bf16 dual-source (k<K1 from Av1 else Av2), per-source row gathers,
//        staged via global_load_lds with inverse-swizzled source.
// ABF=0: A fp32 dual-source, reg-staged convert + swizzled ds_write (fallback)
template<int ABF, int TM>
__global__ __launch_bounds__(256)
void gemm_bt(const void* __restrict__ Av1, long lda1, const int* __restrict__ a1rows,
             const void* __restrict__ Av2, long lda2, const int* __restrict__ a2rows,
             int K1,
             const unsigned short* __restrict__ WT,
             const float* __restrict__ bias,
             const float* __restrict__ Cadd,
             float* __restrict__ C,
             unsigned short* __restrict__ Cbf,
             long ldc, int M, int N, int K, int doGelu) {
    constexpr int MT = TM / 32;          // row-frags per wave
    constexpr int WROWS = TM / 2;
    __shared__ unsigned short As[TM * 64];
    __shared__ unsigned short Bs[128 * 64];
    __shared__ int r1s[TM], r2s[TM];
    int tid = threadIdx.x;
    int bx, by; swz_block(bx, by);
    int row0 = by * TM, col0 = bx * 128;
    if (tid < TM) {
        int gm = row0 + tid; if (gm >= M) gm = M - 1;
        r1s[tid] = a1rows ? a1rows[gm] : gm;
        r2s[tid] = a2rows ? a2rows[gm] : gm;
    }
    int wid = tid >> 6, lane = tid & 63;
    int wr = wid >> 1, wc = wid & 1, llo = lane & 15, lhi = lane >> 4;
    f32x4 acc[MT][4];
#pragma unroll
    for (int i = 0; i < MT; i++)
#pragma unroll
        for (int j = 0; j < 4; j++) acc[i][j] = (f32x4){0.f, 0.f, 0.f, 0.f};
    __syncthreads();

    char* AsB = (char*)As;
    char* BsB = (char*)Bs;
    for (int k0 = 0; k0 < K; k0 += 64) {
        // ---- B stage: gll, source chunk inverse-swizzled ----
#pragma unroll
        for (int i = 0; i < 4; ++i) {
            int q = tid + (i << 8);
            int r = q >> 3, cs = q & 7, c = cs ^ (r & 7);
            gll16(WT + (long)(col0 + r) * K + (k0 + (c << 3)), BsB + (q << 4));
        }
        // ---- A stage ----
        bool s1 = (k0 < K1);
        if (ABF) {
            const unsigned short* Ab = s1 ? (const unsigned short*)Av1
                                          : (const unsigned short*)Av2;
            const long lda = s1 ? lda1 : lda2;
            const int* rsel = s1 ? r1s : r2s;
            const int kb = s1 ? k0 : (k0 - K1);
#pragma unroll
            for (int i = 0; i < MT; ++i) {
                int q = tid + (i << 8);
                int r = q >> 3, cs = q & 7, c = cs ^ (r & 7);
                gll16(Ab + (long)rsel[r] * lda + (kb + (c << 3)), AsB + (q << 4));
            }
        } else {
            const float* A1f = (const float*)Av1;
            const float* A2f = (const float*)Av2;
#pragma unroll
            for (int i = 0; i < MT; ++i) {
                int q = tid + (i << 8);
                int r = q >> 3, c = q & 7;
                const float* src = s1 ? (A1f + (long)r1s[r] * lda1 + (k0 + (c << 3)))
                                      : (A2f + (long)r2s[r] * lda2 + (k0 - K1 + (c << 3)));
                float4v v0 = *(const float4v*)src;
                float4v v1 = *(const float4v*)(src + 4);
                bf16x8 s;
                s[0] = (short)f2bf(v0[0]); s[1] = (short)f2bf(v0[1]);
                s[2] = (short)f2bf(v0[2]); s[3] = (short)f2bf(v0[3]);
                s[4] = (short)f2bf(v1[0]); s[5] = (short)f2bf(v1[1]);
                s[6] = (short)f2bf(v1[2]); s[7] = (short)f2bf(v1[3]);
                *(bf16x8*)(AsB + ((r << 7) + ((c ^ (r & 7)) << 4))) = s;
            }
        }
        __syncthreads();
#pragma unroll
        for (int ks = 0; ks < 2; ++ks) {
            bf16x8 af[MT], bfv[4];
#pragma unroll
            for (int mt = 0; mt < MT; ++mt) {
                int r = wr * WROWS + mt * 16 + llo;
                af[mt] = *(const bf16x8*)(AsB + ((r << 7) + ((((ks << 2) | lhi) ^ (r & 7)) << 4)));
            }
#pragma unroll
            for (int nt = 0; nt < 4; ++nt) {
                int r = wc * 64 + nt * 16 + llo;
                bfv[nt] = *(const bf16x8*)(BsB + ((r << 7) + ((((ks << 2) | lhi) ^ (r & 7)) << 4)));
            }
#pragma unroll
            for (int mt = 0; mt < MT; ++mt)
#pragma unroll
                for (int nt = 0; nt < 4; ++nt)
                    acc[mt][nt] = __builtin_amdgcn_mfma_f32_16x16x32_bf16(
                        af[mt], bfv[nt], acc[mt][nt], 0, 0, 0);
        }
        __syncthreads();
    }
    // epilogue: C/D col=lane&15, row=(lane>>4)*4+reg  [m89-verified]
#pragma unroll
    for (int mt = 0; mt < MT; ++mt) {
#pragma unroll
        for (int nt = 0; nt < 4; ++nt) {
            int gn = col0 + wc * 64 + nt * 16 + llo;
#pragma unroll
            for (int r = 0; r < 4; ++r) {
                int gm = row0 + wr * WROWS + mt * 16 + lhi * 4 + r;
                if (gm >= M) continue;
                float v = acc[mt][nt][r] + bias[gn];
                if (doGelu) v = gelu32(v);
                if (Cadd) v += Cadd[(long)gm * ldc + gn];
                if (C)   C[(long)gm * ldc + gn] = v;
                if (Cbf) Cbf[(long)gm * ldc + gn] = f2bf(v);
            }
        }
    }
}

// ---------------- policy: bf16x3 MFMA GEMM with fused focus-logit dot -------
// AGLL=1: A hi/lo pre-split in global (root_hi/root_lo), staged via gll.
// AGLL=0: A split in-kernel from fp32 root (fallback; identical values).
template<int AGLL>
__global__ __launch_bounds__(256)
void policy_bf16x3(const float* __restrict__ root,
                   const unsigned short* __restrict__ root_hi,
                   const unsigned short* __restrict__ root_lo,
                   const unsigned short* __restrict__ Whi,
                   const unsigned short* __restrict__ Wlo,
                   const float* __restrict__ bp1, const float* __restrict__ wp2m,
                   double* __restrict__ fl64) {
    __shared__ unsigned short Ahi[128 * 64], Alo[128 * 64];
    __shared__ unsigned short Bhi[128 * 64], Blo[128 * 64];
    int tid = threadIdx.x;
    int bx, by; swz_block(bx, by);
    int row0 = by * 128, col0 = bx * 128;
    int wid = tid >> 6, lane = tid & 63;
    int wr = wid >> 1, wc = wid & 1, llo = lane & 15, lhi = lane >> 4;
    f32x4 acc[4][4];
#pragma unroll
    for (int i = 0; i < 4; i++)
#pragma unroll
        for (int j = 0; j < 4; j++) acc[i][j] = (f32x4){0.f, 0.f, 0.f, 0.f};

    char* AhB = (char*)Ahi; char* AlB = (char*)Alo;
    char* BhB = (char*)Bhi; char* BlB = (char*)Blo;
    for (int k0 = 0; k0 < 1024; k0 += 64) {
        // B stage: both splits via gll, inverse-swizzled source
#pragma unroll
        for (int i = 0; i < 4; ++i) {
            int q = tid + (i << 8);
            int r = q >> 3, cs = q & 7, c = cs ^ (r & 7);
            long off = (long)(col0 + r) * 1024 + (k0 + (c << 3));
            gll16(Whi + off, BhB + (q << 4));
            gll16(Wlo + off, BlB + (q << 4));
        }
        // A stage
        if (AGLL) {
#pragma unroll
            for (int i = 0; i < 4; ++i) {
                int q = tid + (i << 8);
                int r = q >> 3, cs = q & 7, c = cs ^ (r & 7);
                long off = (long)(row0 + r) * 1024 + (k0 + (c << 3));
                gll16(root_hi + off, AhB + (q << 4));
                gll16(root_lo + off, AlB + (q << 4));
            }
        } else {
#pragma unroll
            for (int i = 0; i < 4; ++i) {
                int q = tid + (i << 8);
                int r = q >> 3, c = q & 7;
                const float* src = root + (long)(row0 + r) * 1024 + (k0 + (c << 3));
                float4v v0 = *(const float4v*)src;
                float4v v1 = *(const float4v*)(src + 4);
                bf16x8 sh, sl;
#pragma unroll
                for (int e = 0; e < 4; ++e) {
                    unsigned short h0 = f2bf(v0[e]);
                    sh[e] = (short)h0; sl[e] = (short)f2bf(v0[e] - bf2f(h0));
                    unsigned short h1 = f2bf(v1[e]);
                    sh[e + 4] = (short)h1; sl[e + 4] = (short)f2bf(v1[e] - bf2f(h1));
                }
                int off = (r << 7) + ((c ^ (r & 7)) << 4);
                *(bf16x8*)(AhB + off) = sh;
                *(bf16x8*)(AlB + off) = sl;
            }
        }
        __syncthreads();
#pragma unroll
        for (int ks = 0; ks < 2; ++ks) {
            bf16x8 ah[4], al[4], bh[4], bl[4];
#pragma unroll
            for (int mt = 0; mt < 4; ++mt) {
                int r = wr * 64 + mt * 16 + llo;
                int off = (r << 7) + ((((ks << 2) | lhi) ^ (r & 7)) << 4);
                ah[mt] = *(const bf16x8*)(AhB + off);
                al[mt] = *(const bf16x8*)(AlB + off);
            }
#pragma unroll
            for (int nt = 0; nt < 4; ++nt) {
                int r = wc * 64 + nt * 16 + llo;
                int off = (r << 7) + ((((ks << 2) | lhi) ^ (r & 7)) << 4);
                bh[nt] = *(const bf16x8*)(BhB + off);
                bl[nt] = *(const bf16x8*)(BlB + off);
            }
#pragma unroll
            for (int mt = 0; mt < 4; ++mt)
#pragma unroll
                for (int nt = 0; nt < 4; ++nt) {
                    acc[mt][nt] = __builtin_amdgcn_mfma_f32_16x16x32_bf16(
                        ah[mt], bh[nt], acc[mt][nt], 0, 0, 0);
                    acc[mt][nt] = __builtin_amdgcn_mfma_f32_16x16x32_bf16(
                        ah[mt], bl[nt], acc[mt][nt], 0, 0, 0);
                    acc[mt][nt] = __builtin_amdgcn_mfma_f32_16x16x32_bf16(
                        al[mt], bh[nt], acc[mt][nt], 0, 0, 0);
                }
        }
        __syncthreads();
    }
    // epilogue: per-lane row partials (double), reduce over llo, atomicAdd
#pragma unroll
    for (int mt = 0; mt < 4; ++mt) {
        double part[4] = {0.0, 0.0, 0.0, 0.0};
#pragma unroll
        for (int nt = 0; nt < 4; ++nt) {
            int gn = col0 + wc * 64 + nt * 16 + llo;
            float b = bp1[gn], wn = wp2m[gn];
#pragma unroll
            for (int r = 0; r < 4; ++r) {
                float x = acc[mt][nt][r] + b;
                part[r] += (double)gelu32(x) * (double)wn;
            }
        }
#pragma unroll
        for (int r = 0; r < 4; ++r) {
            double v = part[r];
            v += __shfl_xor(v, 1);
            v += __shfl_xor(v, 2);
            v += __shfl_xor(v, 4);
            v += __shfl_xor(v, 8);
            if (llo == 0)
                atomicAdd(&fl64[row0 + wr * 64 + mt * 16 + lhi * 4 + r], v);
        }
    }
}

__global__ void flbuild_kernel(const double* __restrict__ fl64,
                               const float* __restrict__ wp2m,
                               const int* __restrict__ amask,
                               float* __restrict__ fl32) {
    int m = blockIdx.x * 256 + threadIdx.x;
    fl32[m] = (amask[m] == 0) ? -1e9f : (float)(fl64[m] + (double)wp2m[1024]);
}

// --------------------------- small kernels ---------------------------------
__global__ void wp2mean_kernel(const float* __restrict__ Wp2,
                               const float* __restrict__ bp2,
                               float* __restrict__ outv) {
    __shared__ double sb[256];
    int r = blockIdx.x, tid = threadIdx.x;
    const float* src = (r < 1024) ? (Wp2 + (size_t)r * 1024) : bp2;
    double s = 0.0;
    for (int k = tid; k < 1024; k += 256) s += (double)src[k];
    sb[tid] = s; __syncthreads();
    for (int off = 128; off > 0; off >>= 1) {
        if (tid < off) sb[tid] += sb[tid + off];
        __syncthreads();
    }
    if (tid == 0) outv[r] = (float)(sb[0] * (1.0 / 1024.0));
}

__global__ void rootmean_kernel(const float* __restrict__ root, float* __restrict__ rmean,
                                unsigned short* __restrict__ rmean_bf) {
    int b = blockIdx.x;
    int h = blockIdx.y * 256 + threadIdx.x;
    const float* base = root + (size_t)b * SHC + h;
    double s = 0.0;
    for (int ss = 0; ss < SEQ; ss++) s += (double)base[(size_t)ss * HDIM];
    float v = (float)(s * (1.0 / 1024.0));
    rmean[b * HDIM + h] = v;
    if (rmean_bf) rmean_bf[b * HDIM + h] = f2bf(v);
}

__global__ __launch_bounds__(256)
void ctrl_fc1(const float* __restrict__ root, const float* __restrict__ W,
              const float* __restrict__ b1, float* __restrict__ T1) {
    __shared__ double red[16][17];
    int ni = threadIdx.x & 15, kt = threadIdx.x >> 4;
    int n = blockIdx.x * 16 + ni;
    double accb[16];
#pragma unroll
    for (int bb = 0; bb < 16; ++bb) accb[bb] = 0.0;
    for (int k = kt * 64; k < kt * 64 + 64; ++k) {
        double w = (double)W[(long)k * 1024 + n];
#pragma unroll
        for (int bb = 0; bb < 16; ++bb)
            accb[bb] = fma((double)root[(long)bb * SHC + k], w, accb[bb]);
    }
    for (int bb = 0; bb < 16; ++bb) {
        red[kt][ni] = accb[bb];
        __syncthreads();
        if (kt == 0) {
            double s = 0.0;
            for (int q = 0; q < 16; ++q) s += red[q][ni];
            double x = s + (double)b1[n];
            T1[bb * 1024 + n] = (float)(0.5 * x * (1.0 + erf(x * 0.70710678118654752440)));
        }
        __syncthreads();
    }
}

__global__ void ctrl_fc2(const float* __restrict__ T1, const float* __restrict__ W2,
                         const float* __restrict__ b2, float* __restrict__ logits) {
    __shared__ double sb[256];
    int bn = blockIdx.x;
    int b = bn / 5, n = bn % 5;
    double s = 0.0;
    for (int k = threadIdx.x; k < 1024; k += 256)
        s += (double)T1[b * 1024 + k] * (double)W2[k * 5 + n];
    sb[threadIdx.x] = s; __syncthreads();
    for (int off = 128; off > 0; off >>= 1) {
        if (threadIdx.x < off) sb[threadIdx.x] += sb[threadIdx.x + off];
        __syncthreads();
    }
    if (threadIdx.x == 0) logits[b * 5 + n] = (float)(sb[0] + (double)b2[n]);
}

__global__ void sims_kernel(const float* __restrict__ logits, int* __restrict__ sims) {
    int b = threadIdx.x;
    if (b >= BATCH) return;
    float best = logits[b * 5 + 0]; int biv = 0;
    for (int i = 1; i < 5; i++) {
        float v = logits[b * 5 + i];
        if (v > best) { best = v; biv = i; }
    }
    const int opt[5] = {10, 25, 50, 75, 100};
    sims[b] = opt[biv];
}

// Per (t,b): JAX PARTITIONABLE threefry (byte-identical to rounds 5-9)
__global__ void gumbel_kernel(const float* __restrict__ fl,
                              int* __restrict__ idxj, int* __restrict__ vidx) {
    __shared__ float sv[256][3];
    __shared__ int   si[256][3];
    int blk = blockIdx.x;           // c = t*16+b
    int t = blk >> 4, b = blk & 15;
    uint32_t kk0, kk1;
    threefry(0u, 42u, 0u, (uint32_t)t, kk0, kk1);   // fold_in(key(42), t)
    int tid = threadIdx.x;
    float bv[3] = {-INFINITY, -INFINITY, -INFINITY};
    int   bi[3] = {0x7FFFFFFF, 0x7FFFFFFF, 0x7FFFFFFF};
    for (int s = tid; s < SEQ; s += 256) {
        uint32_t m = (uint32_t)(b * SEQ + s);
        uint32_t y0, y1;
        threefry(kk0, kk1, 0u, m, y0, y1);
        uint32_t bits = y0 ^ y1;
        float f = __uint_as_float((bits >> 9) | 0x3F800000u) - 1.0f;
        float u = fmaxf(1.17549435e-38f, f);
        float l1 = (float)log((double)u);
        float l2 = (float)log(-(double)l1);
        float g  = -l2;
        float val = fl[b * SEQ + s] + g;
        if (better(val, s, bv[2], bi[2])) {
            bv[2] = val; bi[2] = s;
            if (better(bv[2], bi[2], bv[1], bi[1])) {
                float tv = bv[1]; int ti = bi[1];
                bv[1] = bv[2]; bi[1] = bi[2]; bv[2] = tv; bi[2] = ti;
            }
            if (better(bv[1], bi[1], bv[0], bi[0])) {
                float tv = bv[0]; int ti = bi[0];
                bv[0] = bv[1]; bi[0] = bi[1]; bv[1] = tv; bi[1] = ti;
            }
        }
    }
    sv[tid][0] = bv[0]; sv[tid][1] = bv[1]; sv[tid][2] = bv[2];
    si[tid][0] = bi[0]; si[tid][1] = bi[1]; si[tid][2] = bi[2];
    __syncthreads();
    for (int off = 128; off > 0; off >>= 1) {
        if (tid < off) {
            float av[3] = {sv[tid][0], sv[tid][1], sv[tid][2]};
            int   ai[3] = {si[tid][0], si[tid][1], si[tid][2]};
            float cv[3] = {sv[tid + off][0], sv[tid + off][1], sv[tid + off][2]};
            int   ci[3] = {si[tid + off][0], si[tid + off][1], si[tid + off][2]};
            float rv[3]; int ri[3]; int pa = 0, pb = 0;
#pragma unroll
            for (int r = 0; r < 3; r++) {
                if (better(av[pa], ai[pa], cv[pb], ci[pb])) { rv[r] = av[pa]; ri[r] = ai[pa]; pa++; }
                else                                        { rv[r] = cv[pb]; ri[r] = ci[pb]; pb++; }
            }
            sv[tid][0] = rv[0]; sv[tid][1] = rv[1]; sv[tid][2] = rv[2];
            si[tid][0] = ri[0]; si[tid][1] = ri[1]; si[tid][2] = ri[2];
        }
        __syncthreads();
    }
    if (tid == 0) {
        idxj[0 * NCHAIN + blk] = b * SEQ + si[0][0];
        idxj[1 * NCHAIN + blk] = b * SEQ + si[0][1];
        idxj[2 * NCHAIN + blk] = b * SEQ + si[0][2];
        vidx[blk] = b;
    }
}

__global__ void meaninit_kernel(const float* __restrict__ rmean, float* __restrict__ mean_cur,
                                unsigned short* __restrict__ mc_bf) {
    int e = blockIdx.x * 256 + threadIdx.x;
    int c = e >> 10, hh = e & 1023;
    float v = rmean[(c & 15) * HDIM + hh];
    mean_cur[e] = v;
    if (mc_bf) mc_bf[e] = f2bf(v);
}

__global__ void meanupd_kernel(const float* __restrict__ NSj, const float* __restrict__ root,
                               const int* __restrict__ idx, float* __restrict__ mean_cur,
                               unsigned short* __restrict__ mc_bf) {
    int e = blockIdx.x * 256 + threadIdx.x;
    int c = e >> 10, hh = e & 1023;
    int r = idx[c];
    double m = (double)mean_cur[e] +
               ((double)NSj[e] - (double)root[(size_t)r * HDIM + hh]) * (1.0 / 1024.0);
    float v = (float)m;
    mean_cur[e] = v;
    if (mc_bf) mc_bf[e] = f2bf(v);
}

__global__ void valdot_kernel(const float* __restrict__ HV, const float* __restrict__ Wav2,
                              const float* __restrict__ bav2, float* __restrict__ w) {
    __shared__ double sb[256];
    int c = blockIdx.x, tid = threadIdx.x;
    double s = 0.0;
    for (int k = tid; k < HDIM; k += 256) s += (double)HV[(size_t)c * HDIM + k] * (double)Wav2[k];
    sb[tid] = s; __syncthreads();
    for (int off = 128; off > 0; off >>= 1) {
        if (tid < off) sb[tid] += sb[tid + off];
        __syncthreads();
    }
    if (tid == 0) {
        double v = sb[0] + (double)bav2[0];
        w[c] = (float)(1.0 / (1.0 + exp(-v)));
    }
}

__global__ void wsum_kernel(const float* __restrict__ w, const int* __restrict__ sims,
                            double* __restrict__ Wsum) {
    int b = threadIdx.x;
    if (b >= BATCH) return;
    int sb = sims[b];
    double s = 0.0;
    for (int t = 0; t < sb; t++) s += (double)w[t * BATCH + b];
    Wsum[b] = s;
}

__global__ void accinit_kernel(const float* __restrict__ root, const double* __restrict__ Wsum,
                               float* __restrict__ acc) {
    size_t e = (size_t)blockIdx.x * 256 + threadIdx.x;
    int b = (int)(e >> 20);
    acc[e] = (float)((1.0 + Wsum[b]) * (double)root[e]);
}

__global__ __launch_bounds__(256)
void corrections_atomic(const float* __restrict__ NS, const float* __restrict__ root,
                        const float* __restrict__ w, const int* __restrict__ sims,
                        const int* __restrict__ idxj, float* __restrict__ acc) {
    int blk = blockIdx.x;                // 0..4799
    int j = blk / NCHAIN, c = blk % NCHAIN;
    int b = c & 15, t = c >> 4;
    if (t >= sims[b]) return;
    float wv = w[c];
    int row = idxj[j * NCHAIN + c];
    const float* ns = NS + ((long)j * NCHAIN + c) * 1024;
    const float* rt = root + (long)row * 1024;
    float* ac = acc + (long)row * 1024;
    for (int h = threadIdx.x; h < 1024; h += 256)
        atomicAdd(&ac[h], wv * (ns[h] - rt[h]));
}

// ------------------------------- launch ------------------------------------
extern "C" void kernel_launch(void* const* d_in, const int* in_sizes, int n_in,
                              void* d_out, int out_size, void* d_ws, size_t ws_size,
                              hipStream_t stream) {
    (void)in_sizes; (void)n_in; (void)out_size;
    const float* root = (const float*)d_in[0];
    const int*   amask = (const int*)d_in[1];
    const float* Wsc1 = (const float*)d_in[2];  const float* bsc1 = (const float*)d_in[3];
    const float* Wsc2 = (const float*)d_in[4];  const float* bsc2 = (const float*)d_in[5];
    const float* Wp1  = (const float*)d_in[6];  const float* bp1  = (const float*)d_in[7];
    const float* Wp2  = (const float*)d_in[8];  const float* bp2  = (const float*)d_in[9];
    const float* Wt1  = (const float*)d_in[10]; const float* bt1  = (const float*)d_in[11];
    const float* Wt2  = (const float*)d_in[12]; const float* bt2  = (const float*)d_in[13];
    const float* Wav1 = (const float*)d_in[14]; const float* bav1 = (const float*)d_in[15];
    const float* Wav2 = (const float*)d_in[16]; const float* bav2 = (const float*)d_in[17];
    const float* Wg1  = (const float*)d_in[18]; const float* bg1  = (const float*)d_in[19];
    const float* Wg2  = (const float*)d_in[20]; const float* bg2  = (const float*)d_in[21];
    float* out = (float*)d_out;

    // ---- workspace carving (base ~57 MB; tier1 +70 MB; tier2 +34 MB) ----
    char* p = (char*)d_ws;
    auto carve = [&](size_t nbytes) -> void* {
        void* r = (void*)p; p += (nbytes + 255) & ~(size_t)255; return r;
    };
    // base region
    float*          mean_cur = (float*)carve((size_t)NCHAIN * HDIM * 4);
    unsigned short* H1bf     = (unsigned short*)carve((size_t)NCHAIN * HDIM * 2);
    float*          Hav      = (float*)carve((size_t)NCHAIN * HDIM * 4);
    float*          NS       = (float*)carve((size_t)3 * NCHAIN * HDIM * 4);
    unsigned short* h_bf     = (unsigned short*)mean_cur;  // aliases 36MB region
    unsigned short* WTt1  = (unsigned short*)carve((size_t)1024 * 2048 * 2);
    unsigned short* WTt2  = (unsigned short*)carve((size_t)1024 * 1024 * 2);
    unsigned short* WTav1 = (unsigned short*)carve((size_t)1024 * 2048 * 2);
    unsigned short* WTg1  = (unsigned short*)carve((size_t)1024 * 2048 * 2);
    unsigned short* WTg2  = (unsigned short*)carve((size_t)1024 * 1024 * 2);
    unsigned short* Wp1hi = (unsigned short*)carve((size_t)1024 * 1024 * 2);
    unsigned short* Wp1lo = (unsigned short*)carve((size_t)1024 * 1024 * 2);
    float*  rmean  = (float*)carve(BATCH * HDIM * 4);
    float*  T1     = (float*)carve(BATCH * HDIM * 4);
    float*  logits = (float*)carve(128 * 4);
    float*  wp2m   = (float*)carve(1040 * 4);
    double* fl64   = (double*)carve((size_t)BATCH * SEQ * 8);
    float*  fl32   = (float*)carve(BATCH * SEQ * 4);
    float*  wbuf   = (float*)carve(NCHAIN * 4);
    double* Wsumd  = (double*)carve(64 * 8);
    int*    sims   = (int*)carve(64 * 4);
    int*    idxj   = (int*)carve(3 * NCHAIN * 4);
    int*    vidx   = (int*)carve(NCHAIN * 4);
    // tier1: bf16 copies of big fp32 operands
    unsigned short* root_bf     = (unsigned short*)carve((size_t)BATCH * SEQ * HDIM * 2);
    unsigned short* acc_bf      = (unsigned short*)carve((size_t)BATCH * SEQ * HDIM * 2);
    unsigned short* mean_cur_bf = (unsigned short*)carve((size_t)NCHAIN * HDIM * 2);
    unsigned short* rmean_bf    = (unsigned short*)carve(BATCH * HDIM * 2);
    size_t tier1_need = (size_t)(p - (char*)d_ws);
    // tier2: lo-split of root for policy gll path
    unsigned short* root_lo = (unsigned short*)carve((size_t)BATCH * SEQ * HDIM * 2);
    size_t tier2_need = (size_t)(p - (char*)d_ws);
    const bool fast1 = ws_size >= tier1_need;
    const bool fast2 = ws_size >= tier2_need;

    const long NTOT8 = (long)BATCH * SEQ * HDIM / 8;

    // 1) weight transposes
    transpose_bf16<<<dim3(2048 / 32, 1024 / 32), 256, 0, stream>>>(Wt1, WTt1, 2048, 1024);
    transpose_bf16<<<dim3(1024 / 32, 1024 / 32), 256, 0, stream>>>(Wt2, WTt2, 1024, 1024);
    transpose_bf16<<<dim3(2048 / 32, 1024 / 32), 256, 0, stream>>>(Wav1, WTav1, 2048, 1024);
    transpose_bf16<<<dim3(2048 / 32, 1024 / 32), 256, 0, stream>>>(Wg1, WTg1, 2048, 1024);
    transpose_bf16<<<dim3(1024 / 32, 1024 / 32), 256, 0, stream>>>(Wg2, WTg2, 1024, 1024);
    transpose_split<<<dim3(1024 / 32, 1024 / 32), 256, 0, stream>>>(Wp1, Wp1hi, Wp1lo, 1024, 1024);
    // 1b) root -> bf16 (hi [+lo]) once
    if (fast1)
        cvt_split<<<2048, 256, 0, stream>>>(root, root_bf, fast2 ? root_lo : nullptr, NTOT8);
    // 2) wp2 means, root mean
    wp2mean_kernel<<<1025, 256, 0, stream>>>(Wp2, bp2, wp2m);
    rootmean_kernel<<<dim3(BATCH, HDIM / 256), 256, 0, stream>>>(
        root, rmean, fast1 ? rmean_bf : nullptr);
    // 3) controller (fp64) -> sims
    ctrl_fc1<<<64, 256, 0, stream>>>(root, Wsc1, bsc1, T1);
    ctrl_fc2<<<80, 256, 0, stream>>>(T1, Wsc2, bsc2, logits);
    sims_kernel<<<1, 64, 0, stream>>>(logits, sims);
    // 4) policy (bf16x3 MFMA, swizzled) + fused focus logits
    hipMemsetAsync(fl64, 0, (size_t)BATCH * SEQ * 8, stream);
    if (fast2)
        policy_bf16x3<1><<<dim3(8, 128), 256, 0, stream>>>(
            root, root_bf, root_lo, Wp1hi, Wp1lo, bp1, wp2m, fl64);
    else
        policy_bf16x3<0><<<dim3(8, 128), 256, 0, stream>>>(
            root, nullptr, nullptr, Wp1hi, Wp1lo, bp1, wp2m, fl64);
    flbuild_kernel<<<BATCH * SEQ / 256, 256, 0, stream>>>(fl64, wp2m, amask, fl32);
    // 5) gumbel top-3 (partitionable threefry, unchanged)
    gumbel_kernel<<<NCHAIN, 256, 0, stream>>>(fl32, idxj, vidx);
    // 6) transitions (TM=64 tiles, swizzled)
    meaninit_kernel<<<NCHAIN * HDIM / 256, 256, 0, stream>>>(
        rmean, mean_cur, fast1 ? mean_cur_bf : nullptr);
    for (int j = 0; j < 3; j++) {
        if (fast1)
            gemm_bt<1, 64><<<dim3(8, 25), 256, 0, stream>>>(
                mean_cur_bf, 1024, nullptr, root_bf, 1024, idxj + j * NCHAIN, 1024,
                WTt1, bt1, nullptr, nullptr, H1bf, 1024, NCHAIN, 1024, 2048, 1);
        else
            gemm_bt<0, 64><<<dim3(8, 25), 256, 0, stream>>>(
                mean_cur, 1024, nullptr, root, 1024, idxj + j * NCHAIN, 1024,
                WTt1, bt1, nullptr, nullptr, H1bf, 1024, NCHAIN, 1024, 2048, 1);
        gemm_bt<1, 64><<<dim3(8, 25), 256, 0, stream>>>(
            H1bf, 1024, nullptr, nullptr, 0, nullptr, 1 << 30,
            WTt2, bt2, nullptr, NS + (size_t)j * NCHAIN * HDIM, nullptr,
            1024, NCHAIN, 1024, 1024, 0);
        meanupd_kernel<<<NCHAIN * HDIM / 256, 256, 0, stream>>>(
            NS + (size_t)j * NCHAIN * HDIM, root, idxj + j * NCHAIN, mean_cur,
            fast1 ? mean_cur_bf : nullptr);
    }
    // 7) action value -> w -> Wsum
    if (fast1)
        gemm_bt<1, 64><<<dim3(8, 25), 256, 0, stream>>>(
            rmean_bf, 1024, vidx, mean_cur_bf, 1024, nullptr, 1024,
            WTav1, bav1, nullptr, Hav, nullptr, 1024, NCHAIN, 1024, 2048, 1);
    else
        gemm_bt<0, 64><<<dim3(8, 25), 256, 0, stream>>>(
            rmean, 1024, vidx, mean_cur, 1024, nullptr, 1024,
            WTav1, bav1, nullptr, Hav, nullptr, 1024, NCHAIN, 1024, 2048, 1);
    valdot_kernel<<<NCHAIN, 256, 0, stream>>>(Hav, Wav2, bav2, wbuf);
    wsum_kernel<<<1, 64, 0, stream>>>(wbuf, sims, Wsumd);
    // 8) acc (in d_out): init + parallel corrections [+ bf16 copy]
    accinit_kernel<<<(BATCH * SEQ * HDIM) / 256, 256, 0, stream>>>(root, Wsumd, out);
    corrections_atomic<<<3 * NCHAIN, 256, 0, stream>>>(NS, root, wbuf, sims, idxj, out);
    if (fast1)
        cvt_split<<<2048, 256, 0, stream>>>(out, acc_bf, nullptr, NTOT8);
    // 9) aggregation (swizzled)
    if (fast1)
        gemm_bt<1, 128><<<dim3(8, 128), 256, 0, stream>>>(
            root_bf, 1024, nullptr, acc_bf, 1024, nullptr, 1024,
            WTg1, bg1, nullptr, nullptr, h_bf, 1024, BATCH * SEQ, 1024, 2048, 1);
    else
        gemm_bt<0, 128><<<dim3(8, 128), 256, 0, stream>>>(
            root, 1024, nullptr, out, 1024, nullptr, 1024,
            WTg1, bg1, nullptr, nullptr, h_bf, 1024, BATCH * SEQ, 1024, 2048, 1);
    gemm_bt<1, 128><<<dim3(8, 128), 256, 0, stream>>>(
        h_bf, 1024, nullptr, nullptr, 0, nullptr, 1 << 30,
        WTg2, bg2, root, out, nullptr, 1024, BATCH * SEQ, 1024, 1024, 0);
}